// Round 6
// baseline (131.830 us; speedup 1.0000x reference)
//
#include <hip/hip_runtime.h>

// Problem constants (fixed shapes from the reference).
constexpr int B = 2, C = 320, H = 128, W = 240;
constexpr int G = 40, CPG = 8, MAXD = 48;
constexpr int HW = H * W;
constexpr int NROW = B * G * H;        // 10240 (b,g,h) rows
constexpr int ROWS_PER_BLOCK = 8;      // 8 waves/block, one row each, consecutive h
constexpr int W4 = W / 4;              // 60 float4 per channel row

typedef float f32x4 __attribute__((ext_vector_type(4)));

// Address-space-qualified void types for global_load_lds.
typedef const __attribute__((address_space(1))) void g_void;
typedef __attribute__((address_space(3))) void lds_void;

// out[b,g,d,h,x] = (1/CPG) * sum_k L[b, g*CPG+k, h, x] * R[b, g*CPG+k, h, x-d]  (x>=d, else 0)
//
// R6 changes vs R5:
//  - Stores back to PLAIN cached stores (nt stores may defeat L2 write
//    aggregation into large HBM bursts; the 7 TB/s fill uses plain stores).
//    Loads stay nontemporal (read-once; don't evict pending write lines).
//  - Sliding-window register carry: hi(dg+1) == lo(dg), so each (k,dg) needs
//    only ONE new ds_read_b128 instead of two -> LDS pipe busy halved
//    (~38us -> ~19us per CU) and shorter per-dg dependence chain.
__global__ __launch_bounds__(512) void gwc_volume_kernel(
    const float* __restrict__ left, const float* __restrict__ right,
    float* __restrict__ out)
{
    const int tid  = threadIdx.x;
    const int wv   = tid >> 6;   // wave id within block -> which row (0..7)
    const int lane = tid & 63;
    const int row  = blockIdx.x * ROWS_PER_BLOCK + wv;

    const int h  = row % H;
    const int bg = row / H;
    const int g  = bg % G;
    const int b  = bg / G;

    // Per-wave staged right row: 8 channels x 60 float4 = 480 float4 (7.68 KB).
    // LINEAR layout (global_load_lds writes base + lane*16, no padding allowed).
    __shared__ f32x4 sR4[ROWS_PER_BLOCK][CPG * W4];

    const size_t in_base = ((size_t)(b * C + g * CPG) * H + h) * (size_t)W;

    const int t = lane;                  // x-tile index, x = 4t..4t+3
    const bool active = (t < W4);        // lanes 60..63 help staging + barriers only

    // ---- issue LEFT loads first (registers), so they fly with R staging ----
    f32x4 Lv[CPG];
    if (active) {
        #pragma unroll
        for (int k = 0; k < CPG; ++k)
            Lv[k] = __builtin_nontemporal_load(
                reinterpret_cast<const f32x4*>(left + in_base + (size_t)k * HW + 4 * t));
    }

    // ---- stage RIGHT row: direct HBM -> LDS, 8 x (64 lanes x 16 B) chunks ----
    #pragma unroll
    for (int i = 0; i < 8; ++i) {
        const int j = i * 64 + lane;     // float4 index: j = k*60 + x4
        if (j < CPG * W4) {
            const int k  = j / W4;
            const int x4 = j - k * W4;
            const float* src = right + in_base + (size_t)k * HW + 4 * x4;
            char* dst = (char*)&sR4[wv][0] + (size_t)i * 1024;
            __builtin_amdgcn_global_load_lds((g_void*)src, (lds_void*)dst, 16, 0, 0);
        }
    }

    // One drain for BOTH batches (L regs + LDS staging), then compute.
    asm volatile("s_waitcnt vmcnt(0)" ::: "memory");
    __builtin_amdgcn_sched_barrier(0);

    const f32x4* sr = &sR4[wv][0];
    float* outp = out + (((size_t)(b * G + g) * MAXD) * H + h) * (size_t)W + 4 * t;

    // Sliding-window carry: Hc[k] holds R[A .. A+3] for the CURRENT dg
    // (A = 4*(t-dg)); after each dg it becomes the next dg's hi.
    f32x4 Hc[CPG];
    if (active) {
        #pragma unroll
        for (int k = 0; k < CPG; ++k) Hc[k] = sr[k * W4 + t];  // dg=0 hi
    }

    // ---- 12 disparity groups of 4 ----
    #pragma unroll 2
    for (int dg = 0; dg < MAXD / 4; ++dg) {
        // Temporal write clustering across the block's 8 waves — raw barrier,
        // no vmcnt drain (stores stay in flight; waves share no LDS).
        __builtin_amdgcn_s_barrier();

        float acc[4][4];
        #pragma unroll
        for (int dd = 0; dd < 4; ++dd)
            #pragma unroll
            for (int xx = 0; xx < 4; ++xx) acc[dd][xx] = 0.f;

        if (active && t >= dg) {         // t < dg: whole tile in the zero wedge
            #pragma unroll
            for (int k = 0; k < CPG; ++k) {
                const f32x4 hi = Hc[k];                      // R[A .. A+3]
                f32x4 lo;                                    // R[A-4 .. A-1]
                if (t > dg) lo = sr[k * W4 + (t - dg) - 1];  // one NEW read per (k,dg)
                else        lo = (f32x4){0.f, 0.f, 0.f, 0.f}; // x<d -> zeros
                float win[8];
                win[0] = lo.x; win[1] = lo.y; win[2] = lo.z; win[3] = lo.w;
                win[4] = hi.x; win[5] = hi.y; win[6] = hi.z; win[7] = hi.w;
                // r-index = A + xx - dd -> win[4 + xx - dd]
                #pragma unroll
                for (int dd = 0; dd < 4; ++dd)
                    #pragma unroll
                    for (int xx = 0; xx < 4; ++xx)
                        acc[dd][xx] += Lv[k][xx] * win[4 + xx - dd];
                Hc[k] = lo;              // slide: next dg's hi
            }
        }

        if (active) {
            float* op = outp + (size_t)(dg * 4) * HW;
            #pragma unroll
            for (int dd = 0; dd < 4; ++dd) {
                f32x4 o;
                o.x = acc[dd][0] * 0.125f;
                o.y = acc[dd][1] * 0.125f;
                o.z = acc[dd][2] * 0.125f;
                o.w = acc[dd][3] * 0.125f;
                // Plain cached store: let L2 aggregate the write stream.
                *reinterpret_cast<f32x4*>(op + (size_t)dd * HW) = o;
            }
        }
    }
}

extern "C" void kernel_launch(void* const* d_in, const int* in_sizes, int n_in,
                              void* d_out, int out_size, void* d_ws, size_t ws_size,
                              hipStream_t stream) {
    const float* left  = (const float*)d_in[0];
    const float* right = (const float*)d_in[1];
    float* out = (float*)d_out;

    dim3 grid(NROW / ROWS_PER_BLOCK);   // 1280 blocks
    dim3 block(512);                    // 8 waves, 8 consecutive h rows of one (b,g)
    hipLaunchKernelGGL(gwc_volume_kernel, grid, block, 0, stream,
                       left, right, out);
}

// Round 7
// 117.707 us; speedup vs baseline: 1.1200x; 1.1200x over previous
//
#include <hip/hip_runtime.h>

// Problem constants (fixed shapes from the reference).
constexpr int B = 2, C = 320, H = 128, W = 240;
constexpr int G = 40, CPG = 8, MAXD = 48;
constexpr int HW = H * W;
constexpr int NROW = B * G * H;        // 10240 (b,g,h) rows
constexpr int ROWS_PER_BLOCK = 8;      // 8 waves/block, one row each, consecutive h
constexpr int W4 = W / 4;              // 60 float4 per channel row

typedef float f32x4 __attribute__((ext_vector_type(4)));

// Address-space-qualified void types for global_load_lds.
typedef const __attribute__((address_space(1))) void g_void;
typedef __attribute__((address_space(3))) void lds_void;

// out[b,g,d,h,x] = (1/CPG) * sum_k L[b, g*CPG+k, h, x] * R[b, g*CPG+k, h, x-d]  (x>=d, else 0)
//
// R7 = R5 core (nt stores, no sliding window — both R6 changes reverted) +
// LDS write-coalescing: computing lanes ds_write results to a block buffer;
// all 512 threads then store each (d, 8-row) 7680B chunk tid-linearly ->
// dense 1024B-aligned 64-lane bursts instead of 8 misaligned 960B bursts.
// Two dd-pair phases keep LDS at 76.8KB -> 2 blocks/CU (16 waves, = R5).
// All barriers are lgkm-only: stores stay in flight (R5's key win kept).
__global__ __launch_bounds__(512) void gwc_volume_kernel(
    const float* __restrict__ left, const float* __restrict__ right,
    float* __restrict__ out)
{
    const int tid  = threadIdx.x;
    const int wv   = tid >> 6;   // wave id within block -> which row (0..7)
    const int lane = tid & 63;
    const int row  = blockIdx.x * ROWS_PER_BLOCK + wv;

    const int h  = row % H;
    const int h0 = h - wv;       // block's first h row (8 | H, never straddles (b,g))
    const int bg = row / H;
    const int g  = bg % G;
    const int b  = bg / G;

    // Staged right rows: 8 waves x 480 float4 = 61.4 KB (linear, gload_lds dest).
    __shared__ f32x4 sR4[ROWS_PER_BLOCK][CPG * W4];
    // Write-coalescing buffer for one dd-pair: [ddl][row][x4] = 15.4 KB.
    __shared__ f32x4 wb[2][ROWS_PER_BLOCK][W4];

    const size_t in_base = ((size_t)(b * C + g * CPG) * H + h) * (size_t)W;

    const int t = lane;                  // x-tile index, x = 4t..4t+3
    const bool active = (t < W4);        // lanes 60..63: staging + coop store only

    // ---- issue LEFT loads first (registers), so they fly with R staging ----
    f32x4 Lv[CPG];
    if (active) {
        #pragma unroll
        for (int k = 0; k < CPG; ++k)
            Lv[k] = __builtin_nontemporal_load(
                reinterpret_cast<const f32x4*>(left + in_base + (size_t)k * HW + 4 * t));
    }

    // ---- stage RIGHT row: direct HBM -> LDS, 8 x (64 lanes x 16 B) chunks ----
    #pragma unroll
    for (int i = 0; i < 8; ++i) {
        const int j = i * 64 + lane;     // float4 index: j = k*60 + x4
        if (j < CPG * W4) {
            const int k  = j / W4;
            const int x4 = j - k * W4;
            const float* src = right + in_base + (size_t)k * HW + 4 * x4;
            char* dst = (char*)&sR4[wv][0] + (size_t)i * 1024;
            __builtin_amdgcn_global_load_lds((g_void*)src, (lds_void*)dst, 16, 0, 0);
        }
    }

    // One drain for BOTH batches (L regs + LDS staging), then compute.
    asm volatile("s_waitcnt vmcnt(0)" ::: "memory");
    __builtin_amdgcn_sched_barrier(0);

    const f32x4* sr = &sR4[wv][0];
    const f32x4* wbflat = &wb[0][0][0];
    // Base (in floats) of the block's 8-row chunk in d-slice 0 of this (b,g).
    const size_t chunk00 = ((size_t)bg * MAXD * H + h0) * (size_t)W;

    // ---- 12 disparity groups of 4 ----
    #pragma unroll 1
    for (int dg = 0; dg < MAXD / 4; ++dg) {
        float acc[4][4];
        #pragma unroll
        for (int dd = 0; dd < 4; ++dd)
            #pragma unroll
            for (int xx = 0; xx < 4; ++xx) acc[dd][xx] = 0.f;

        if (active && t >= dg) {         // t < dg: whole tile in the zero wedge
            #pragma unroll
            for (int k = 0; k < CPG; ++k) {
                const int base = k * W4 + (t - dg);
                const f32x4 hi = sr[base];                   // R[A .. A+3]
                f32x4 lo;
                if (t > dg) lo = sr[base - 1];               // R[A-4 .. A-1]
                else        lo = (f32x4){0.f, 0.f, 0.f, 0.f}; // x<d -> zeros
                float win[8];
                win[0] = lo.x; win[1] = lo.y; win[2] = lo.z; win[3] = lo.w;
                win[4] = hi.x; win[5] = hi.y; win[6] = hi.z; win[7] = hi.w;
                // r-index = A + xx - dd -> win[4 + xx - dd]
                #pragma unroll
                for (int dd = 0; dd < 4; ++dd)
                    #pragma unroll
                    for (int xx = 0; xx < 4; ++xx)
                        acc[dd][xx] += Lv[k][xx] * win[4 + xx - dd];
            }
        }

        // ---- two dd-pair writeback phases through LDS ----
        #pragma unroll
        for (int phase = 0; phase < 2; ++phase) {
            if (active) {
                #pragma unroll
                for (int ddl = 0; ddl < 2; ++ddl) {
                    const int dd = phase * 2 + ddl;
                    f32x4 o;
                    o.x = acc[dd][0] * 0.125f;
                    o.y = acc[dd][1] * 0.125f;
                    o.z = acc[dd][2] * 0.125f;
                    o.w = acc[dd][3] * 0.125f;
                    wb[ddl][wv][t] = o;
                }
            }
            asm volatile("s_waitcnt lgkmcnt(0)" ::: "memory");
            __builtin_amdgcn_s_barrier();
            __builtin_amdgcn_sched_barrier(0);

            // Cooperative dense store: 960 float4 (2 slices x 8 rows x 960B),
            // tid-linear -> full 1024B-aligned 64-lane bursts.
            const int d_base = dg * 4 + phase * 2;
            const size_t cbase = chunk00 + (size_t)d_base * HW;  // floats
            {
                const int f   = tid;                 // 0..511
                const int ddl = f / 480;
                const int rem = f - ddl * 480;
                const f32x4 v = wbflat[f];
                __builtin_nontemporal_store(
                    v, reinterpret_cast<f32x4*>(out + cbase + (size_t)ddl * HW + 4 * rem));
            }
            if (tid < 960 - 512) {                   // second sweep: f = tid+512
                const int f   = tid + 512;           // 512..959 -> ddl=1
                const int rem = f - 480;
                const f32x4 v = wbflat[f];
                __builtin_nontemporal_store(
                    v, reinterpret_cast<f32x4*>(out + cbase + (size_t)HW + 4 * rem));
            }

            asm volatile("s_waitcnt lgkmcnt(0)" ::: "memory");
            __builtin_amdgcn_s_barrier();            // wb reusable next phase
            __builtin_amdgcn_sched_barrier(0);
        }
    }
}

extern "C" void kernel_launch(void* const* d_in, const int* in_sizes, int n_in,
                              void* d_out, int out_size, void* d_ws, size_t ws_size,
                              hipStream_t stream) {
    const float* left  = (const float*)d_in[0];
    const float* right = (const float*)d_in[1];
    float* out = (float*)d_out;

    dim3 grid(NROW / ROWS_PER_BLOCK);   // 1280 blocks
    dim3 block(512);                    // 8 waves, 8 consecutive h rows of one (b,g)
    hipLaunchKernelGGL(gwc_volume_kernel, grid, block, 0, stream,
                       left, right, out);
}